// Round 10
// baseline (228.290 us; speedup 1.0000x reference)
//
#include <hip/hip_runtime.h>

#define F_IN 64
#define NH 4
#define HC 128
#define NEG_SLOPE 0.2f
#define LN_EPS 1e-5f
#define NC_CHUNK 128          // number of edge chunks
#define BUCKET 128            // dst nodes per bucket
#define WT_LD 72              // padded LDS leading dim for Wt (2-way aliasing = free)

typedef __bf16 bf16_8 __attribute__((ext_vector_type(8)));
typedef float  f32_4  __attribute__((ext_vector_type(4)));

// ---------------------------------------------------------------------------
// K0: detect whether edge_index arrived as int64 (little-endian) or int32.
// ---------------------------------------------------------------------------
__global__ void k0_detect(const int* __restrict__ ei, int E, int* __restrict__ flag) {
    __shared__ int any_nz;
    if (threadIdx.x == 0) any_nz = 0;
    __syncthreads();
    long long stride = (2LL * E) / 257;
    long long pos = (long long)(threadIdx.x + 1) * stride;
    int w = ei[pos | 1];
    if (w != 0) atomicOr(&any_nz, 1);
    __syncthreads();
    if (threadIdx.x == 0) flag[0] = (any_nz == 0) ? 1 : 0;   // 1 => int64
}

__device__ inline unsigned bfpack(float a, float b) {
    unsigned ua = __float_as_uint(a), ub = __float_as_uint(b);
    ua = (ua + 0x7fffu + ((ua >> 16) & 1u)) >> 16;           // RNE to bf16
    ub = (ub + 0x7fffu + ((ub >> 16) & 1u)) >> 16;
    return ua | (ub << 16);
}

__device__ inline float wave_bcast_sum(float v) {
#pragma unroll
    for (int off = 32; off > 0; off >>= 1) v += __shfl_down(v, off, 64);
    return __shfl(v, 0, 64);
}

// ---------------------------------------------------------------------------
// KA (MFMA): h_bf16 = x@W, r_bf16 = x@res_w, + fused attention logits.
// A = Wcat^T in LDS [256 ch x WT_LD k] bf16; B = x rows (bf16x8 frags).
// Verified layouts: A[m=lane&15][k=quad*8+j], B[k=quad*8+j][n=lane&15],
// D[row=quad*4+reg][col=lane&15]. Wave = 16 nodes x 256 cols.
// ---------------------------------------------------------------------------
__global__ __launch_bounds__(256) void kA_mfma(
    const float* __restrict__ x, const float* __restrict__ W,
    const float* __restrict__ res_w,
    const float* __restrict__ att_src, const float* __restrict__ att_dst,
    unsigned* __restrict__ h_bf, unsigned* __restrict__ r_bf,
    float* __restrict__ a_s, float* __restrict__ a_d, int n)
{
    __shared__ __bf16 Ws[256 * WT_LD];          // 36 KB
    int tid = threadIdx.x;
    {
        // W, res_w: [64 rows x 128 cols] f32 = 2048 float4 each (32 float4/row)
        const float4* W4 = (const float4*)W;
        const float4* R4 = (const float4*)res_w;
#pragma unroll
        for (int it = 0; it < 8; ++it) {
            int idx = it * 256 + tid;           // 0..2047
            int k = idx >> 5;                   // row of W (32 float4 per row)
            int c = (idx & 31) * 4;             // col of W (0..124)
            float4 wv = W4[idx];
            Ws[(c + 0) * WT_LD + k] = (__bf16)wv.x;
            Ws[(c + 1) * WT_LD + k] = (__bf16)wv.y;
            Ws[(c + 2) * WT_LD + k] = (__bf16)wv.z;
            Ws[(c + 3) * WT_LD + k] = (__bf16)wv.w;
            float4 rv = R4[idx];
            Ws[(128 + c + 0) * WT_LD + k] = (__bf16)rv.x;
            Ws[(128 + c + 1) * WT_LD + k] = (__bf16)rv.y;
            Ws[(128 + c + 2) * WT_LD + k] = (__bf16)rv.z;
            Ws[(128 + c + 3) * WT_LD + k] = (__bf16)rv.w;
        }
    }
    __syncthreads();

    int wv_ = tid >> 6, lane = tid & 63;
    int col = lane & 15, quad = lane >> 4;
    int node = blockIdx.x * 64 + wv_ * 16 + col;
    int nrow = (node < n) ? node : (n - 1);

    // B-frags: x[nrow][quad*8 + (0..7)] for k-halves 0 (k+0) and 1 (k+32)
    bf16_8 bx0, bx1;
    {
        const float* xp = &x[nrow * F_IN + quad * 8];
        float4 p0 = *(const float4*)(xp);
        float4 p1 = *(const float4*)(xp + 4);
        float4 p2 = *(const float4*)(xp + 32);
        float4 p3 = *(const float4*)(xp + 36);
        bx0[0] = (__bf16)p0.x; bx0[1] = (__bf16)p0.y; bx0[2] = (__bf16)p0.z; bx0[3] = (__bf16)p0.w;
        bx0[4] = (__bf16)p1.x; bx0[5] = (__bf16)p1.y; bx0[6] = (__bf16)p1.z; bx0[7] = (__bf16)p1.w;
        bx1[0] = (__bf16)p2.x; bx1[1] = (__bf16)p2.y; bx1[2] = (__bf16)p2.z; bx1[3] = (__bf16)p2.w;
        bx1[4] = (__bf16)p3.x; bx1[5] = (__bf16)p3.y; bx1[6] = (__bf16)p3.z; bx1[7] = (__bf16)p3.w;
    }

    float vs[4] = {0.f, 0.f, 0.f, 0.f};
    float vd[4] = {0.f, 0.f, 0.f, 0.f};

#pragma unroll
    for (int mt = 0; mt < 16; ++mt) {
        const __bf16* ap = &Ws[(mt * 16 + col) * WT_LD + quad * 8];
        bf16_8 a0 = *(const bf16_8*)ap;
        bf16_8 a1 = *(const bf16_8*)(ap + 32);
        f32_4 acc = {0.f, 0.f, 0.f, 0.f};
        acc = __builtin_amdgcn_mfma_f32_16x16x32_bf16(a0, bx0, acc, 0, 0, 0);
        acc = __builtin_amdgcn_mfma_f32_16x16x32_bf16(a1, bx1, acc, 0, 0, 0);
        int ch0 = mt * 16 + quad * 4;
        if (mt < 8) {
            float4 as4 = *(const float4*)&att_src[ch0];
            float4 ad4 = *(const float4*)&att_dst[ch0];
            int head = mt >> 1;
            vs[head] += acc[0] * as4.x + acc[1] * as4.y + acc[2] * as4.z + acc[3] * as4.w;
            vd[head] += acc[0] * ad4.x + acc[1] * ad4.y + acc[2] * ad4.z + acc[3] * ad4.w;
            if (node < n) {
                uint2 pk = make_uint2(bfpack(acc[0], acc[1]), bfpack(acc[2], acc[3]));
                *(uint2*)&h_bf[node * 64 + (ch0 >> 1)] = pk;
            }
        } else {
            if (node < n) {
                uint2 pk = make_uint2(bfpack(acc[0], acc[1]), bfpack(acc[2], acc[3]));
                *(uint2*)&r_bf[node * 64 + ((ch0 - 128) >> 1)] = pk;
            }
        }
    }

#pragma unroll
    for (int hh = 0; hh < NH; ++hh) {
        vs[hh] += __shfl_down(vs[hh], 32, 64);
        vs[hh] += __shfl_down(vs[hh], 16, 64);
        vd[hh] += __shfl_down(vd[hh], 32, 64);
        vd[hh] += __shfl_down(vd[hh], 16, 64);
    }
    if (quad == 0 && node < n) {
        *(float4*)&a_s[node * NH] = make_float4(vs[0], vs[1], vs[2], vs[3]);
        *(float4*)&a_d[node * NH] = make_float4(vd[0], vd[1], vd[2], vd[3]);
    }
}

// ---------------------------------------------------------------------------
// KC_count: chunk c histograms ITS OWN edges by dst bucket (LDS); also folds
// scan-phase-1 by atomically adding each cell into its 256-chunk bsum.
// ---------------------------------------------------------------------------
__global__ __launch_bounds__(256) void kc_count(
    const int* __restrict__ ei, int E, const int* __restrict__ flag,
    int* __restrict__ counts, int* __restrict__ bsums, int NB, int chunk)
{
    __shared__ int cnt[512];
    int c = blockIdx.x;
    for (int i = threadIdx.x; i < NB; i += 256) cnt[i] = 0;
    __syncthreads();
    int base = c * chunk, end = min(E, base + chunk);
    int is64 = flag[0];
    for (int idx = base + threadIdx.x; idx < end; idx += 256) {
        int d = is64 ? ei[2 * (E + idx)] : ei[E + idx];
        atomicAdd(&cnt[d >> 7], 1);
    }
    __syncthreads();
    for (int b = threadIdx.x; b < NB; b += 256) {
        int v = cnt[b];
        counts[b * NC_CHUNK + c] = v;
        if (v) atomicAdd(&bsums[(b * NC_CHUNK + c) >> 8], v);
    }
}

__global__ __launch_bounds__(256) void k_scan_p2(int* __restrict__ bsums, int nblk)
{
    __shared__ int sh[256];
    int t = threadIdx.x;
    int v = (t < nblk) ? bsums[t] : 0;
    sh[t] = v;
    __syncthreads();
#pragma unroll
    for (int off = 1; off < 256; off <<= 1) {
        int u = (t >= off) ? sh[t - off] : 0;
        __syncthreads();
        sh[t] += u;
        __syncthreads();
    }
    if (t < nblk) bsums[t] = sh[t] - v;
}

__global__ __launch_bounds__(256) void k_scan_p3(int* __restrict__ arr,
                                                 const int* __restrict__ bsums,
                                                 int M, int E)
{
    __shared__ int sh[256];
    int t = threadIdx.x;
    int i = blockIdx.x * 256 + t;
    int v = (i < M) ? arr[i] : 0;
    sh[t] = v;
    __syncthreads();
#pragma unroll
    for (int off = 1; off < 256; off <<= 1) {
        int u = (t >= off) ? sh[t - off] : 0;
        __syncthreads();
        sh[t] += u;
        __syncthreads();
    }
    int excl = sh[t] - v + bsums[blockIdx.x];
    if (i < M) arr[i] = excl;
    if (blockIdx.x == 0 && t == 0) arr[M] = E;
}

// ---------------------------------------------------------------------------
// KC_scatter: chunk c writes packed (dst_local<<16 | src) into its private
// per-bucket slices (LDS cursors). Requires n <= 65536.
// ---------------------------------------------------------------------------
__global__ __launch_bounds__(1024) void kc_scatter(
    const int* __restrict__ ei, int E, const int* __restrict__ flag,
    const int* __restrict__ off, int NB, int chunk, int* __restrict__ epacked)
{
    __shared__ int cur[512];
    int c = blockIdx.x;
    for (int b = threadIdx.x; b < NB; b += 1024) cur[b] = off[b * NC_CHUNK + c];
    __syncthreads();
    int base = c * chunk, end = min(E, base + chunk);
    int is64 = flag[0];
    for (int idx = base + threadIdx.x; idx < end; idx += 1024) {
        int s = is64 ? ei[2 * idx] : ei[idx];
        int d = is64 ? ei[2 * (E + idx)] : ei[E + idx];
        int p = atomicAdd(&cur[d >> 7], 1);
        epacked[p] = ((d & (BUCKET - 1)) << 16) | s;
    }
}

// ---------------------------------------------------------------------------
// KD_sort: one block per bucket -> per-dst CSR order within the bucket's
// private global range; emits node-level offsets.
// ---------------------------------------------------------------------------
__global__ __launch_bounds__(256) void kd_sort(
    const int* __restrict__ off, const int* __restrict__ epacked,
    int* __restrict__ sorted_src, int* __restrict__ offsets,
    int NB, int n, int E)
{
    __shared__ int hist[BUCKET];
    __shared__ int sc[BUCKET];
    __shared__ int cur[BUCKET];
    int b = blockIdx.x;
    int s0 = off[b * NC_CHUNK];
    int s1 = off[(b + 1) * NC_CHUNK];
    int t = threadIdx.x;
    if (t < BUCKET) hist[t] = 0;
    __syncthreads();
    for (int e = s0 + t; e < s1; e += 256)
        atomicAdd(&hist[((unsigned)epacked[e]) >> 16], 1);
    __syncthreads();
    if (t < BUCKET) sc[t] = hist[t];
    __syncthreads();
#pragma unroll
    for (int o = 1; o < BUCKET; o <<= 1) {
        int u = (t >= o && t < BUCKET) ? sc[t - o] : 0;
        __syncthreads();
        if (t < BUCKET) sc[t] += u;
        __syncthreads();
    }
    if (t < BUCKET) {
        int excl = sc[t] - hist[t];
        cur[t] = s0 + excl;
        int d = b * BUCKET + t;
        if (d < n) offsets[d] = s0 + excl;
    }
    if (b == NB - 1 && t == 0) offsets[n] = E;
    __syncthreads();
    for (int e = s0 + t; e < s1; e += 256) {
        int p = epacked[e];
        int pos = atomicAdd(&cur[((unsigned)p) >> 16], 1);
        sorted_src[pos] = p & 0xFFFF;
    }
}

// ---------------------------------------------------------------------------
// K_agg: wave-per-dst CSR gather, register accumulation, fused epilogue.
// ---------------------------------------------------------------------------
__global__ __launch_bounds__(256) void k_agg(
    const int* __restrict__ offsets, const int* __restrict__ src_sorted,
    const float* __restrict__ a_s, const float* __restrict__ a_d,
    const unsigned int* __restrict__ h_bf, const unsigned int* __restrict__ r_bf,
    const float* __restrict__ bias, const float* __restrict__ res_b,
    const float* __restrict__ ln_g, const float* __restrict__ ln_b,
    float* __restrict__ out, int n)
{
    int wv = threadIdx.x >> 6, lane = threadIdx.x & 63;
    int d = blockIdx.x * 4 + wv;
    if (d >= n) return;
    int c0 = lane * 2, head = lane >> 4;
    float ad = a_d[d * NH + head];

    // self-loop
    float e = a_s[d * NH + head] + ad;
    e = (e >= 0.f) ? e : NEG_SLOPE * e;
    float w = __expf(e);
    float denom = w;
    unsigned hv = h_bf[d * 64 + lane];
    float ax = w * __uint_as_float(hv << 16);
    float ay = w * __uint_as_float(hv & 0xffff0000u);

    int lo = offsets[d], hi = offsets[d + 1];
    int k = lo;
    for (; k + 7 < hi; k += 8) {
        int s[8]; unsigned v[8]; float ee[8];
#pragma unroll
        for (int i = 0; i < 8; ++i) s[i] = src_sorted[k + i];
#pragma unroll
        for (int i = 0; i < 8; ++i) ee[i] = a_s[s[i] * NH + head];
#pragma unroll
        for (int i = 0; i < 8; ++i) v[i] = h_bf[s[i] * 64 + lane];
#pragma unroll
        for (int i = 0; i < 8; ++i) {
            float e0 = ee[i] + ad;
            e0 = (e0 >= 0.f) ? e0 : NEG_SLOPE * e0;
            float w0 = __expf(e0);
            denom += w0;
            ax += w0 * __uint_as_float(v[i] << 16);
            ay += w0 * __uint_as_float(v[i] & 0xffff0000u);
        }
    }
    for (; k < hi; ++k) {
        int s0 = src_sorted[k];
        float e0 = a_s[s0 * NH + head] + ad;
        unsigned v0 = h_bf[s0 * 64 + lane];
        e0 = (e0 >= 0.f) ? e0 : NEG_SLOPE * e0;
        float w0 = __expf(e0);
        denom += w0;
        ax += w0 * __uint_as_float(v0 << 16);
        ay += w0 * __uint_as_float(v0 & 0xffff0000u);
    }

    float inv = 1.f / denom;
    float ox = ax * inv + bias[c0];
    float oy = ay * inv + bias[c0 + 1];
    ox = (ox > 0.f) ? ox : expm1f(ox);
    oy = (oy > 0.f) ? oy : expm1f(oy);
    unsigned rv = r_bf[d * 64 + lane];
    ox += __uint_as_float(rv << 16) + res_b[c0];
    oy += __uint_as_float(rv & 0xffff0000u) + res_b[c0 + 1];
    float mean = wave_bcast_sum(ox + oy) * (1.f / HC);
    float dx = ox - mean, dy = oy - mean;
    float var = wave_bcast_sum(dx * dx + dy * dy) * (1.f / HC);
    float rs = rsqrtf(var + LN_EPS);
    *(float2*)&out[d * HC + c0] =
        make_float2(ln_g[c0] * dx * rs + ln_b[c0],
                    ln_g[c0 + 1] * dy * rs + ln_b[c0 + 1]);
}

// ---------------------------------------------------------------------------
extern "C" void kernel_launch(void* const* d_in, const int* in_sizes, int n_in,
                              void* d_out, int out_size, void* d_ws, size_t ws_size,
                              hipStream_t stream) {
    const float* x       = (const float*)d_in[0];
    const int*   ei      = (const int*)d_in[1];
    const float* W       = (const float*)d_in[2];
    const float* att_src = (const float*)d_in[3];
    const float* att_dst = (const float*)d_in[4];
    const float* bias    = (const float*)d_in[5];
    const float* res_w   = (const float*)d_in[6];
    const float* res_b   = (const float*)d_in[7];
    const float* ln_g    = (const float*)d_in[8];
    const float* ln_b    = (const float*)d_in[9];
    float* out = (float*)d_out;

    int n = in_sizes[0] / F_IN;              // 50000 (<= 65536 for packing)
    int E = in_sizes[1] / 2;                 // 800000
    int NB = (n + BUCKET - 1) / BUCKET;      // 391 buckets (<= 512)
    int chunk = (E + NC_CHUNK - 1) / NC_CHUNK;
    int M = NB * NC_CHUNK;                   // 50048
    int nblk = (M + 255) / 256;              // 196 (<= 256)

    unsigned* h_bf     = (unsigned*)d_ws;                  // n*64 dwords
    unsigned* r_bf     = h_bf + (size_t)n * 64;            // n*64 dwords
    float*    a_s      = (float*)(r_bf + (size_t)n * 64);  // n*NH
    float*    a_d      = a_s + (size_t)n * NH;             // n*NH
    int*      off      = (int*)(a_d + (size_t)n * NH);     // M+1
    int*      bsums    = off + (M + 1);                    // 256
    int*      epacked  = bsums + 256;                      // E
    int*      ssorted  = epacked + E;                      // E
    int*      offsets  = ssorted + E;                      // n+1
    int*      flag     = offsets + (n + 1);                // 1

    hipMemsetAsync(bsums, 0, 256 * sizeof(int), stream);

    k0_detect<<<1, 256, 0, stream>>>(ei, E, flag);

    kA_mfma<<<(n + 63) / 64, 256, 0, stream>>>(
        x, W, res_w, att_src, att_dst, h_bf, r_bf, a_s, a_d, n);

    kc_count<<<NC_CHUNK, 256, 0, stream>>>(ei, E, flag, off, bsums, NB, chunk);

    k_scan_p2<<<1, 256, 0, stream>>>(bsums, nblk);
    k_scan_p3<<<nblk, 256, 0, stream>>>(off, bsums, M, E);

    kc_scatter<<<NC_CHUNK, 1024, 0, stream>>>(ei, E, flag, off, NB, chunk, epacked);

    kd_sort<<<NB, 256, 0, stream>>>(off, epacked, ssorted, offsets, NB, n, E);

    k_agg<<<(n + 3) / 4, 256, 0, stream>>>(offsets, ssorted, a_s, a_d, h_bf, r_bf,
                                           bias, res_b, ln_g, ln_b, out, n);
}